// Round 1
// baseline (254.451 us; speedup 1.0000x reference)
//
#include <hip/hip_runtime.h>
#include <math.h>

#define VOX (128*128*128)
#define NCH 48

__device__ __forceinline__ float waveSum(float v) {
#pragma unroll
    for (int off = 32; off > 0; off >>= 1) v += __shfl_down(v, off, 64);
    return v;
}

// ---------------- zero accumulators (ws is poisoned 0xAA each launch) -------
__global__ void zero_acc(float* acc) {
    acc[threadIdx.x] = 0.0f;   // 64 floats
}

// ---------------- dice reduction -------------------------------------------
// acc[b*6 + {0..5}] = inter1, inter2, psum1, psum2, cnt1, cnt2
__global__ __launch_bounds__(256) void dice_kernel(const float* __restrict__ pred,
                                                   const int* __restrict__ target,
                                                   float* __restrict__ acc) {
    const int b = blockIdx.z;
    const float4* p0 = (const float4*)(pred + (size_t)b * 3 * VOX);
    const float4* p1 = (const float4*)(pred + (size_t)b * 3 * VOX + VOX);
    const float4* p2 = (const float4*)(pred + (size_t)b * 3 * VOX + 2 * VOX);
    const int4*   tg = (const int4*)(target + (size_t)b * VOX);

    float vals[6] = {0, 0, 0, 0, 0, 0};
    const int V4 = VOX / 4;
    const int stride = gridDim.x * blockDim.x;
    for (int v = blockIdx.x * blockDim.x + threadIdx.x; v < V4; v += stride) {
        float4 a = p0[v], bq = p1[v], cq = p2[v];
        int4 t = tg[v];
        float xs[4][3] = {{a.x, bq.x, cq.x}, {a.y, bq.y, cq.y},
                          {a.z, bq.z, cq.z}, {a.w, bq.w, cq.w}};
        int ts[4] = {t.x, t.y, t.z, t.w};
#pragma unroll
        for (int e = 0; e < 4; e++) {
            float x0 = xs[e][0], x1 = xs[e][1], x2 = xs[e][2];
            float m = fmaxf(x0, fmaxf(x1, x2));
            float e0 = __expf(x0 - m), e1 = __expf(x1 - m), e2 = __expf(x2 - m);
            float inv = 1.0f / (e0 + e1 + e2);
            float q1 = e1 * inv, q2 = e2 * inv;
            vals[2] += q1;
            vals[3] += q2;
            int tt = ts[e];
            vals[0] += (tt == 1) ? q1 : 0.0f;
            vals[1] += (tt == 2) ? q2 : 0.0f;
            vals[4] += (tt == 1) ? 1.0f : 0.0f;
            vals[5] += (tt == 2) ? 1.0f : 0.0f;
        }
    }
    __shared__ float red[4][6];
    int lane = threadIdx.x & 63, wid = threadIdx.x >> 6;
#pragma unroll
    for (int k = 0; k < 6; k++) {
        float s = waveSum(vals[k]);
        if (lane == 0) red[wid][k] = s;
    }
    __syncthreads();
    if (threadIdx.x < 6) {
        float s = red[0][threadIdx.x] + red[1][threadIdx.x] +
                  red[2][threadIdx.x] + red[3][threadIdx.x];
        atomicAdd(&acc[b * 6 + threadIdx.x], s);
    }
}

// ---------------- normalize features + extract mask classes + counts -------
// acc[12 + (scale*2+b)*8 + {0..7}] = S11,S22,S12,S01,S02,c0,c1,c2
__global__ __launch_bounds__(256) void norm_kernel(const float* __restrict__ f0in,
                                                   const float* __restrict__ f1in,
                                                   const float* __restrict__ f2in,
                                                   const int* __restrict__ target,
                                                   float* __restrict__ f0out,
                                                   float* __restrict__ f1out,
                                                   float* __restrict__ f2out,
                                                   int* __restrict__ cls0,
                                                   int* __restrict__ cls1,
                                                   int* __restrict__ cls2,
                                                   float* __restrict__ acc) {
    const int scale = blockIdx.y, b = blockIdx.z;
    const int N = (scale == 0) ? 4096 : (scale == 1) ? 512 : 64;
    if ((int)(blockIdx.x * blockDim.x) >= N) return;  // block-uniform exit
    const int n = blockIdx.x * blockDim.x + threadIdx.x;

    int myCls = -1;
    if (n < N) {
        const float* fi = ((scale == 0) ? f0in : (scale == 1) ? f1in : f2in)
                          + (size_t)b * NCH * N + n;
        float* fo = ((scale == 0) ? f0out : (scale == 1) ? f1out : f2out)
                    + (size_t)b * NCH * N + n;
        float v[NCH];
        float ss = 0.0f;
#pragma unroll
        for (int c = 0; c < NCH; c++) { v[c] = fi[(size_t)c * N]; ss += v[c] * v[c]; }
        float inv = 1.0f / fmaxf(sqrtf(ss), 1e-12f);
#pragma unroll
        for (int c = 0; c < NCH; c++) fo[(size_t)c * N] = v[c] * inv;

        const int d = (scale == 0) ? 16 : (scale == 1) ? 8 : 4;
        const int s = 128 / d;
        int i3 = n % d, i2 = (n / d) % d, i1 = n / (d * d);
        int t = target[(size_t)b * VOX + (size_t)(i1 * s) * 16384 + (i2 * s) * 128 + (i3 * s)];
        ((scale == 0) ? cls0 : (scale == 1) ? cls1 : cls2)[b * N + n] = t;
        myCls = t;
    }
    float* cnt = &acc[12 + (scale * 2 + b) * 8 + 5];
#pragma unroll
    for (int k = 0; k < 3; k++) {
        unsigned long long mb = __ballot(myCls == k);
        if ((threadIdx.x & 63) == 0 && mb)
            atomicAdd(&cnt[k], (float)__popcll(mb));
    }
}

// ---------------- pair-sum kernel (the Gram reduction) ----------------------
// grid (64,64,6): z = scale*2 + b; 64x64 tile, 256 threads, 4x4 per thread
__global__ __launch_bounds__(256) void pair_kernel(const float* __restrict__ f0,
                                                   const float* __restrict__ f1,
                                                   const float* __restrict__ f2,
                                                   const int* __restrict__ cls0,
                                                   const int* __restrict__ cls1,
                                                   const int* __restrict__ cls2,
                                                   float* __restrict__ acc) {
    const int z = blockIdx.z;
    const int scale = z >> 1, b = z & 1;
    const int N = (scale == 0) ? 4096 : (scale == 1) ? 512 : 64;
    const int tiles = N >> 6;
    if ((int)blockIdx.x >= tiles || (int)blockIdx.y >= tiles) return;

    __shared__ float Fi[NCH][64];
    __shared__ float Fj[NCH][64];
    __shared__ int Ci[64], Cj[64];

    const float* fb = ((scale == 0) ? f0 : (scale == 1) ? f1 : f2) + (size_t)b * NCH * N;
    const int* cb = ((scale == 0) ? cls0 : (scale == 1) ? cls1 : cls2) + b * N;
    const int i0 = blockIdx.x * 64, j0 = blockIdx.y * 64;
    const int t = threadIdx.x;

    for (int idx = t; idx < NCH * 64; idx += 256) {
        int k = idx >> 6, n = idx & 63;
        Fi[k][n] = fb[(size_t)k * N + i0 + n];
        Fj[k][n] = fb[(size_t)k * N + j0 + n];
    }
    if (t < 64) { Ci[t] = cb[i0 + t]; Cj[t] = cb[j0 + t]; }
    __syncthreads();

    const int tx = t & 15, ty = t >> 4;
    const int ib = ty * 4, jb = tx * 4;
    float dot[4][4] = {};
#pragma unroll 4
    for (int k = 0; k < NCH; k++) {
        float4 av = *(const float4*)(&Fi[k][ib]);
        float4 bv = *(const float4*)(&Fj[k][jb]);
        float ai[4] = {av.x, av.y, av.z, av.w};
        float bj[4] = {bv.x, bv.y, bv.z, bv.w};
#pragma unroll
        for (int ii = 0; ii < 4; ii++)
#pragma unroll
            for (int jj = 0; jj < 4; jj++)
                dot[ii][jj] += ai[ii] * bj[jj];
    }

    int ci[4], cj[4], gi[4], gj[4];
#pragma unroll
    for (int ii = 0; ii < 4; ii++) { ci[ii] = Ci[ib + ii]; gi[ii] = i0 + ib + ii; }
#pragma unroll
    for (int jj = 0; jj < 4; jj++) { cj[jj] = Cj[jb + jj]; gj[jj] = j0 + jb + jj; }

    float s[5] = {0, 0, 0, 0, 0};
#pragma unroll
    for (int ii = 0; ii < 4; ii++) {
#pragma unroll
        for (int jj = 0; jj < 4; jj++) {
            float e = __expf(dot[ii][jj] * 10.0f);
            bool nd = gi[ii] != gj[jj];
            s[0] += (ci[ii] == 1 && cj[jj] == 1 && nd) ? e : 0.0f;
            s[1] += (ci[ii] == 2 && cj[jj] == 2 && nd) ? e : 0.0f;
            s[2] += (ci[ii] == 1 && cj[jj] == 2) ? e : 0.0f;
            s[3] += (ci[ii] == 0 && cj[jj] == 1) ? e : 0.0f;
            s[4] += (ci[ii] == 0 && cj[jj] == 2) ? e : 0.0f;
        }
    }

    __shared__ float red[4][5];
    int lane = t & 63, wid = t >> 6;
#pragma unroll
    for (int k = 0; k < 5; k++) {
        float r = waveSum(s[k]);
        if (lane == 0) red[wid][k] = r;
    }
    __syncthreads();
    if (t < 5) {
        float r = red[0][t] + red[1][t] + red[2][t] + red[3][t];
        atomicAdd(&acc[12 + (scale * 2 + b) * 8 + t], r);
    }
}

// ---------------- finalize ---------------------------------------------------
__global__ void finalize_kernel(const float* __restrict__ acc,
                                const float* __restrict__ logits,
                                const int* __restrict__ labels,
                                float* __restrict__ out) {
    if (threadIdx.x != 0 || blockIdx.x != 0) return;
    // dice
    float dsum = 0.0f;
    for (int b = 0; b < 2; b++)
        for (int c = 0; c < 2; c++) {
            float inter = acc[b * 6 + c];
            float psum  = acc[b * 6 + 2 + c];
            float cnt   = acc[b * 6 + 4 + c];
            dsum += (2.0f * inter + 1e-5f) / (psum + cnt + 1e-5f);
        }
    float dice = 1.0f - dsum * 0.25f;
    // focal
    float fsum = 0.0f;
    for (int i = 0; i < 6; i++) {
        float x = logits[i];
        float pt = 1.0f / (1.0f + __expf(-x));
        if (labels[i] != 1) pt = 1.0f - pt;
        fsum += -0.25f * (1.0f - pt) * (1.0f - pt) * logf(pt + 1e-6f);
    }
    float focal = fsum * (1.0f / 6.0f);
    // contrastive
    const float sw[3] = {1.0f, 0.8f, 0.6f};
    float contr = 0.0f;
    for (int sc = 0; sc < 3; sc++) {
        float bsum = 0.0f;
        for (int b = 0; b < 2; b++) {
            const float* a = &acc[12 + (sc * 2 + b) * 8];
            float S11 = a[0], S22 = a[1], S12 = a[2], S01 = a[3], S02 = a[4];
            float c0 = a[5], c1 = a[6], c2 = a[7];
            float l = 0.0f, cnt, mean;
            cnt = c1 * c1 - c1; mean = S11 / fmaxf(cnt, 1.0f);
            l += (cnt > 0.0f) ? -logf(mean + 1e-6f) : 0.0f;
            cnt = c2 * c2 - c2; mean = S22 / fmaxf(cnt, 1.0f);
            l += (cnt > 0.0f) ? -logf(mean + 1e-6f) : 0.0f;
            cnt = c1 * c2; mean = S12 / fmaxf(cnt, 1.0f);
            l += (cnt > 0.0f) ? log1pf(mean) : 0.0f;
            cnt = c0 * c1; mean = S01 / fmaxf(cnt, 1.0f);
            l += (cnt > 0.0f) ? log1pf(mean) : 0.0f;
            cnt = c0 * c2; mean = S02 / fmaxf(cnt, 1.0f);
            l += (cnt > 0.0f) ? log1pf(mean) : 0.0f;
            bsum += l;
        }
        contr += sw[sc] * bsum * 0.5f;
    }
    float total = dice + focal + 0.1f * contr;
    out[0] = total;
    out[1] = dice;
    out[2] = focal;
    out[3] = contr;
}

// ---------------- launch -----------------------------------------------------
extern "C" void kernel_launch(void* const* d_in, const int* in_sizes, int n_in,
                              void* d_out, int out_size, void* d_ws, size_t ws_size,
                              hipStream_t stream) {
    const float* pred   = (const float*)d_in[0];
    const int*   target = (const int*)d_in[1];
    const float* f0     = (const float*)d_in[2];
    const float* f1     = (const float*)d_in[3];
    const float* f2     = (const float*)d_in[4];
    const float* logits = (const float*)d_in[5];
    const int*   labels = (const int*)d_in[6];
    float* out = (float*)d_out;

    char* ws = (char*)d_ws;
    float* acc = (float*)ws;                                   // 64 floats
    int* cls0 = (int*)(ws + 1024);                             // 2*4096 ints
    int* cls1 = (int*)(ws + 1024 + 32768);                     // 2*512 ints
    int* cls2 = (int*)(ws + 1024 + 32768 + 4096);              // 2*64 ints
    float* fo0 = (float*)(ws + 65536);                         // 2*48*4096 floats
    float* fo1 = (float*)(ws + 65536 + 1572864);               // 2*48*512 floats
    float* fo2 = (float*)(ws + 65536 + 1572864 + 196608);      // 2*48*64 floats

    zero_acc<<<dim3(1), dim3(64), 0, stream>>>(acc);
    dice_kernel<<<dim3(512, 1, 2), dim3(256), 0, stream>>>(pred, target, acc);
    norm_kernel<<<dim3(16, 3, 2), dim3(256), 0, stream>>>(f0, f1, f2, target,
                                                          fo0, fo1, fo2,
                                                          cls0, cls1, cls2, acc);
    pair_kernel<<<dim3(64, 64, 6), dim3(256), 0, stream>>>(fo0, fo1, fo2,
                                                           cls0, cls1, cls2, acc);
    finalize_kernel<<<dim3(1), dim3(64), 0, stream>>>(acc, logits, labels, out);
}

// Round 2
// 225.595 us; speedup vs baseline: 1.1279x; 1.1279x over previous
//
#include <hip/hip_runtime.h>
#include <math.h>

#define VOX (128*128*128)
#define NCH 48

typedef _Float16 half8 __attribute__((ext_vector_type(8)));
typedef float floatx4 __attribute__((ext_vector_type(4)));

__device__ __forceinline__ float waveSum(float v) {
#pragma unroll
    for (int off = 32; off > 0; off >>= 1) v += __shfl_down(v, off, 64);
    return v;
}

// ---------------- zero accumulators (ws is poisoned 0xAA each launch) -------
__global__ void zero_acc(float* acc) {
    acc[threadIdx.x] = 0.0f;   // 64 floats
}

// ---------------- dice reduction -------------------------------------------
// acc[b*6 + {0..5}] = inter1, inter2, psum1, psum2, cnt1, cnt2
__global__ __launch_bounds__(256) void dice_kernel(const float* __restrict__ pred,
                                                   const int* __restrict__ target,
                                                   float* __restrict__ acc) {
    const int b = blockIdx.z;
    const float4* p0 = (const float4*)(pred + (size_t)b * 3 * VOX);
    const float4* p1 = (const float4*)(pred + (size_t)b * 3 * VOX + VOX);
    const float4* p2 = (const float4*)(pred + (size_t)b * 3 * VOX + 2 * VOX);
    const int4*   tg = (const int4*)(target + (size_t)b * VOX);

    float vals[6] = {0, 0, 0, 0, 0, 0};
    const int V4 = VOX / 4;
    const int stride = gridDim.x * blockDim.x;
    for (int v = blockIdx.x * blockDim.x + threadIdx.x; v < V4; v += stride) {
        float4 a = p0[v], bq = p1[v], cq = p2[v];
        int4 t = tg[v];
        float xs[4][3] = {{a.x, bq.x, cq.x}, {a.y, bq.y, cq.y},
                          {a.z, bq.z, cq.z}, {a.w, bq.w, cq.w}};
        int ts[4] = {t.x, t.y, t.z, t.w};
#pragma unroll
        for (int e = 0; e < 4; e++) {
            float x0 = xs[e][0], x1 = xs[e][1], x2 = xs[e][2];
            float m = fmaxf(x0, fmaxf(x1, x2));
            float e0 = __expf(x0 - m), e1 = __expf(x1 - m), e2 = __expf(x2 - m);
            float inv = 1.0f / (e0 + e1 + e2);
            float q1 = e1 * inv, q2 = e2 * inv;
            vals[2] += q1;
            vals[3] += q2;
            int tt = ts[e];
            vals[0] += (tt == 1) ? q1 : 0.0f;
            vals[1] += (tt == 2) ? q2 : 0.0f;
            vals[4] += (tt == 1) ? 1.0f : 0.0f;
            vals[5] += (tt == 2) ? 1.0f : 0.0f;
        }
    }
    __shared__ float red[4][6];
    int lane = threadIdx.x & 63, wid = threadIdx.x >> 6;
#pragma unroll
    for (int k = 0; k < 6; k++) {
        float s = waveSum(vals[k]);
        if (lane == 0) red[wid][k] = s;
    }
    __syncthreads();
    if (threadIdx.x < 6) {
        float s = red[0][threadIdx.x] + red[1][threadIdx.x] +
                  red[2][threadIdx.x] + red[3][threadIdx.x];
        atomicAdd(&acc[b * 6 + threadIdx.x], s);
    }
}

// ---------------- normalize features -> fp16 [n][64], classes, counts ------
// acc[12 + z*8 + {0..7}] = S11,S22,S12,S01,S02,c0,c1,c2   (z = scale*2+b)
__global__ __launch_bounds__(256) void norm_kernel(const float* __restrict__ f0in,
                                                   const float* __restrict__ f1in,
                                                   const float* __restrict__ f2in,
                                                   const int* __restrict__ target,
                                                   _Float16* __restrict__ Fh0,
                                                   _Float16* __restrict__ Fh1,
                                                   _Float16* __restrict__ Fh2,
                                                   int* __restrict__ cls0,
                                                   int* __restrict__ cls1,
                                                   int* __restrict__ cls2,
                                                   float* __restrict__ acc) {
    const int scale = blockIdx.y, b = blockIdx.z;
    const int N    = (scale == 0) ? 4096 : (scale == 1) ? 512 : 64;
    const int Npad = (scale == 0) ? 4096 : (scale == 1) ? 512 : 128;
    if ((int)(blockIdx.x * blockDim.x) >= Npad) return;  // block-uniform exit
    const int n = blockIdx.x * blockDim.x + threadIdx.x;

    int myCls = -1;
    if (n < Npad) {
        _Float16* fo = ((scale == 0) ? Fh0 : (scale == 1) ? Fh1 : Fh2)
                       + (size_t)b * Npad * 64 + (size_t)n * 64;
        int* cls = ((scale == 0) ? cls0 : (scale == 1) ? cls1 : cls2) + b * Npad;
        if (n < N) {
            const float* fi = ((scale == 0) ? f0in : (scale == 1) ? f1in : f2in)
                              + (size_t)b * NCH * N + n;
            float v[NCH];
            float ss = 0.0f;
#pragma unroll
            for (int c = 0; c < NCH; c++) { v[c] = fi[(size_t)c * N]; ss += v[c] * v[c]; }
            float inv = 1.0f / fmaxf(sqrtf(ss), 1e-12f);
#pragma unroll
            for (int g = 0; g < 8; g++) {
                half8 h;
#pragma unroll
                for (int e = 0; e < 8; e++) {
                    int c = g * 8 + e;
                    h[e] = (c < NCH) ? (_Float16)(v[c] * inv) : (_Float16)0.0f;
                }
                *(half8*)(fo + g * 8) = h;
            }
            const int d = (scale == 0) ? 16 : (scale == 1) ? 8 : 4;
            const int s = 128 / d;
            int i3 = n % d, i2 = (n / d) % d, i1 = n / (d * d);
            int t = target[(size_t)b * VOX + (size_t)(i1 * s) * 16384 + (i2 * s) * 128 + (i3 * s)];
            cls[n] = t;
            myCls = t;
        } else {
            half8 h = {};
#pragma unroll
            for (int g = 0; g < 8; g++) *(half8*)(fo + g * 8) = h;
            cls[n] = 255;
        }
    }
    float* cnt = &acc[12 + (scale * 2 + b) * 8 + 5];
#pragma unroll
    for (int k = 0; k < 3; k++) {
        unsigned long long mb = __ballot(myCls == k);
        if ((threadIdx.x & 63) == 0 && mb)
            atomicAdd(&cnt[k], (float)__popcll(mb));
    }
}

// ---------------- MFMA pair-sum kernel (triangle, fp16 Gram) ----------------
// block = 256 thr = 4 waves in 2x2, block tile 128x128, wave tile 64x64
// only upper triangle (i<j); off-diag pair counted once, doubled for S11/S22
__global__ __launch_bounds__(256) void pair_mfma(const _Float16* __restrict__ Fh0,
                                                 const _Float16* __restrict__ Fh1,
                                                 const _Float16* __restrict__ Fh2,
                                                 const int* __restrict__ cls0,
                                                 const int* __restrict__ cls1,
                                                 const int* __restrict__ cls2,
                                                 float* __restrict__ acc) {
    const int z = blockIdx.z;
    const int scale = z >> 1, b = z & 1;
    const int Npad = (scale == 0) ? 4096 : (scale == 1) ? 512 : 128;
    const int tiles = Npad >> 7;
    const int bx = blockIdx.x, by = blockIdx.y;
    if (bx >= tiles || by >= tiles || bx > by) return;

    const _Float16* F = ((scale == 0) ? Fh0 : (scale == 1) ? Fh1 : Fh2)
                        + (size_t)b * Npad * 64;
    const int* C = ((scale == 0) ? cls0 : (scale == 1) ? cls1 : cls2) + b * Npad;

    const int tid = threadIdx.x, lane = tid & 63, w = tid >> 6;
    const int wi = w >> 1, wj = w & 1;
    const int ib = bx * 128 + wi * 64, jb = by * 128 + wj * 64;
    const int m = lane & 15, q = lane >> 4;

    floatx4 acc_[4][4] = {};
    const _Float16* Ai = F + (size_t)(ib + m) * 64 + q * 8;
    const _Float16* Bj = F + (size_t)(jb + m) * 64 + q * 8;

    half8 aF[2][4], bF[2][4];
#pragma unroll
    for (int k = 0; k < 2; k++)
#pragma unroll
        for (int t = 0; t < 4; t++) {
            aF[k][t] = *(const half8*)(Ai + t * 16 * 64 + k * 32);
            bF[k][t] = *(const half8*)(Bj + t * 16 * 64 + k * 32);
        }
#pragma unroll
    for (int k = 0; k < 2; k++)
#pragma unroll
        for (int ti = 0; ti < 4; ti++)
#pragma unroll
            for (int tj = 0; tj < 4; tj++)
                acc_[ti][tj] = __builtin_amdgcn_mfma_f32_16x16x32_f16(
                    aF[k][ti], bF[k][tj], acc_[ti][tj], 0, 0, 0);

    // classes for my output elements (C/D layout: col=lane&15, row=q*4+reg)
    int cjr[4], cir[4][4];
#pragma unroll
    for (int tj = 0; tj < 4; tj++) cjr[tj] = C[jb + tj * 16 + m];
#pragma unroll
    for (int ti = 0; ti < 4; ti++)
#pragma unroll
        for (int r = 0; r < 4; r++) cir[ti][r] = C[ib + ti * 16 + q * 4 + r];

    float s[5] = {0, 0, 0, 0, 0};
#pragma unroll
    for (int ti = 0; ti < 4; ti++) {
#pragma unroll
        for (int tj = 0; tj < 4; tj++) {
#pragma unroll
            for (int r = 0; r < 4; r++) {
                int gi = ib + ti * 16 + q * 4 + r;
                int gj = jb + tj * 16 + m;
                float e = __expf(acc_[ti][tj][r] * 10.0f);
                bool tri = gi < gj;
                int ci = cir[ti][r], cj = cjr[tj];
                int ss = ci + cj, pp = ci * cj;
                s[0] += (tri && pp == 1) ? e + e : 0.0f;
                s[1] += (tri && pp == 4) ? e + e : 0.0f;
                s[2] += (tri && ss == 3) ? e : 0.0f;
                s[3] += (tri && ss == 1) ? e : 0.0f;
                s[4] += (tri && ss == 2 && pp == 0) ? e : 0.0f;
            }
        }
    }

    __shared__ float red[4][5];
#pragma unroll
    for (int k = 0; k < 5; k++) {
        float r = waveSum(s[k]);
        if (lane == 0) red[w][k] = r;
    }
    __syncthreads();
    if (tid < 5) {
        float r = red[0][tid] + red[1][tid] + red[2][tid] + red[3][tid];
        atomicAdd(&acc[12 + z * 8 + tid], r);
    }
}

// ---------------- finalize ---------------------------------------------------
__global__ void finalize_kernel(const float* __restrict__ acc,
                                const float* __restrict__ logits,
                                const int* __restrict__ labels,
                                float* __restrict__ out) {
    if (threadIdx.x != 0 || blockIdx.x != 0) return;
    // dice
    float dsum = 0.0f;
    for (int b = 0; b < 2; b++)
        for (int c = 0; c < 2; c++) {
            float inter = acc[b * 6 + c];
            float psum  = acc[b * 6 + 2 + c];
            float cnt   = acc[b * 6 + 4 + c];
            dsum += (2.0f * inter + 1e-5f) / (psum + cnt + 1e-5f);
        }
    float dice = 1.0f - dsum * 0.25f;
    // focal
    float fsum = 0.0f;
    for (int i = 0; i < 6; i++) {
        float x = logits[i];
        float pt = 1.0f / (1.0f + __expf(-x));
        if (labels[i] != 1) pt = 1.0f - pt;
        fsum += -0.25f * (1.0f - pt) * (1.0f - pt) * logf(pt + 1e-6f);
    }
    float focal = fsum * (1.0f / 6.0f);
    // contrastive
    const float sw[3] = {1.0f, 0.8f, 0.6f};
    float contr = 0.0f;
    for (int sc = 0; sc < 3; sc++) {
        float bsum = 0.0f;
        for (int b = 0; b < 2; b++) {
            const float* a = &acc[12 + (sc * 2 + b) * 8];
            float S11 = a[0], S22 = a[1], S12 = a[2], S01 = a[3], S02 = a[4];
            float c0 = a[5], c1 = a[6], c2 = a[7];
            float l = 0.0f, cnt, mean;
            cnt = c1 * c1 - c1; mean = S11 / fmaxf(cnt, 1.0f);
            l += (cnt > 0.0f) ? -logf(mean + 1e-6f) : 0.0f;
            cnt = c2 * c2 - c2; mean = S22 / fmaxf(cnt, 1.0f);
            l += (cnt > 0.0f) ? -logf(mean + 1e-6f) : 0.0f;
            cnt = c1 * c2; mean = S12 / fmaxf(cnt, 1.0f);
            l += (cnt > 0.0f) ? log1pf(mean) : 0.0f;
            cnt = c0 * c1; mean = S01 / fmaxf(cnt, 1.0f);
            l += (cnt > 0.0f) ? log1pf(mean) : 0.0f;
            cnt = c0 * c2; mean = S02 / fmaxf(cnt, 1.0f);
            l += (cnt > 0.0f) ? log1pf(mean) : 0.0f;
            bsum += l;
        }
        contr += sw[sc] * bsum * 0.5f;
    }
    float total = dice + focal + 0.1f * contr;
    out[0] = total;
    out[1] = dice;
    out[2] = focal;
    out[3] = contr;
}

// ---------------- launch -----------------------------------------------------
extern "C" void kernel_launch(void* const* d_in, const int* in_sizes, int n_in,
                              void* d_out, int out_size, void* d_ws, size_t ws_size,
                              hipStream_t stream) {
    const float* pred   = (const float*)d_in[0];
    const int*   target = (const int*)d_in[1];
    const float* f0     = (const float*)d_in[2];
    const float* f1     = (const float*)d_in[3];
    const float* f2     = (const float*)d_in[4];
    const float* logits = (const float*)d_in[5];
    const int*   labels = (const int*)d_in[6];
    float* out = (float*)d_out;

    char* ws = (char*)d_ws;
    float* acc = (float*)ws;                         // 64 floats @ 0
    int* cls0 = (int*)(ws + 1024);                   // 2*4096 ints
    int* cls1 = (int*)(ws + 1024 + 32768);           // 2*512 ints
    int* cls2 = (int*)(ws + 1024 + 32768 + 4096);    // 2*128 ints
    _Float16* Fh0 = (_Float16*)(ws + 40960);                      // 2*4096*64
    _Float16* Fh1 = (_Float16*)(ws + 40960 + 1048576);            // 2*512*64
    _Float16* Fh2 = (_Float16*)(ws + 40960 + 1048576 + 131072);   // 2*128*64

    zero_acc<<<dim3(1), dim3(64), 0, stream>>>(acc);
    dice_kernel<<<dim3(512, 1, 2), dim3(256), 0, stream>>>(pred, target, acc);
    norm_kernel<<<dim3(16, 3, 2), dim3(256), 0, stream>>>(f0, f1, f2, target,
                                                          Fh0, Fh1, Fh2,
                                                          cls0, cls1, cls2, acc);
    pair_mfma<<<dim3(32, 32, 6), dim3(256), 0, stream>>>(Fh0, Fh1, Fh2,
                                                         cls0, cls1, cls2, acc);
    finalize_kernel<<<dim3(1), dim3(64), 0, stream>>>(acc, logits, labels, out);
}

// Round 3
// 166.467 us; speedup vs baseline: 1.5285x; 1.3552x over previous
//
#include <hip/hip_runtime.h>
#include <math.h>

#define VOX (128*128*128)
#define NCH 48

typedef _Float16 half8 __attribute__((ext_vector_type(8)));
typedef float floatx4 __attribute__((ext_vector_type(4)));

__device__ __forceinline__ float waveSum(float v) {
#pragma unroll
    for (int off = 32; off > 0; off >>= 1) v += __shfl_down(v, off, 64);
    return v;
}

// acc layout: [0..11] dice (b*6+k); [12 + z*16 + {0..7}] = S11,S22,S12,S01,S02,c0,c1,c2
// z slots padded to 16 floats (64B) so atomics from different z never share a line.

__global__ void zero_acc(float* acc) {
    acc[threadIdx.x] = 0.0f;
    acc[threadIdx.x + 64] = 0.0f;   // 128 floats
}

// ---------------- dice reduction -------------------------------------------
__global__ __launch_bounds__(256) void dice_kernel(const float* __restrict__ pred,
                                                   const int* __restrict__ target,
                                                   float* __restrict__ acc) {
    const int b = blockIdx.z;
    const float4* p0 = (const float4*)(pred + (size_t)b * 3 * VOX);
    const float4* p1 = (const float4*)(pred + (size_t)b * 3 * VOX + VOX);
    const float4* p2 = (const float4*)(pred + (size_t)b * 3 * VOX + 2 * VOX);
    const int4*   tg = (const int4*)(target + (size_t)b * VOX);

    float vals[6] = {0, 0, 0, 0, 0, 0};
    const int V4 = VOX / 4;
    const int stride = gridDim.x * blockDim.x;
    for (int v = blockIdx.x * blockDim.x + threadIdx.x; v < V4; v += stride) {
        float4 a = p0[v], bq = p1[v], cq = p2[v];
        int4 t = tg[v];
        float xs[4][3] = {{a.x, bq.x, cq.x}, {a.y, bq.y, cq.y},
                          {a.z, bq.z, cq.z}, {a.w, bq.w, cq.w}};
        int ts[4] = {t.x, t.y, t.z, t.w};
#pragma unroll
        for (int e = 0; e < 4; e++) {
            float x0 = xs[e][0], x1 = xs[e][1], x2 = xs[e][2];
            float m = fmaxf(x0, fmaxf(x1, x2));
            float e0 = __expf(x0 - m), e1 = __expf(x1 - m), e2 = __expf(x2 - m);
            float inv = 1.0f / (e0 + e1 + e2);
            float q1 = e1 * inv, q2 = e2 * inv;
            vals[2] += q1;
            vals[3] += q2;
            int tt = ts[e];
            vals[0] += (tt == 1) ? q1 : 0.0f;
            vals[1] += (tt == 2) ? q2 : 0.0f;
            vals[4] += (tt == 1) ? 1.0f : 0.0f;
            vals[5] += (tt == 2) ? 1.0f : 0.0f;
        }
    }
    __shared__ float red[4][6];
    int lane = threadIdx.x & 63, wid = threadIdx.x >> 6;
#pragma unroll
    for (int k = 0; k < 6; k++) {
        float s = waveSum(vals[k]);
        if (lane == 0) red[wid][k] = s;
    }
    __syncthreads();
    if (threadIdx.x < 6) {
        float s = red[0][threadIdx.x] + red[1][threadIdx.x] +
                  red[2][threadIdx.x] + red[3][threadIdx.x];
        atomicAdd(&acc[b * 6 + threadIdx.x], s);
    }
}

// ---------------- normalize features -> fp16 [n][64], classes, counts ------
__global__ __launch_bounds__(256) void norm_kernel(const float* __restrict__ f0in,
                                                   const float* __restrict__ f1in,
                                                   const float* __restrict__ f2in,
                                                   const int* __restrict__ target,
                                                   _Float16* __restrict__ Fh0,
                                                   _Float16* __restrict__ Fh1,
                                                   _Float16* __restrict__ Fh2,
                                                   int* __restrict__ cls0,
                                                   int* __restrict__ cls1,
                                                   int* __restrict__ cls2,
                                                   float* __restrict__ acc) {
    const int scale = blockIdx.y, b = blockIdx.z;
    const int N    = (scale == 0) ? 4096 : (scale == 1) ? 512 : 64;
    const int Npad = (scale == 0) ? 4096 : (scale == 1) ? 512 : 128;
    if ((int)(blockIdx.x * blockDim.x) >= Npad) return;  // block-uniform exit
    const int n = blockIdx.x * blockDim.x + threadIdx.x;

    int myCls = -1;
    if (n < Npad) {
        _Float16* fo = ((scale == 0) ? Fh0 : (scale == 1) ? Fh1 : Fh2)
                       + (size_t)b * Npad * 64 + (size_t)n * 64;
        int* cls = ((scale == 0) ? cls0 : (scale == 1) ? cls1 : cls2) + b * Npad;
        if (n < N) {
            const float* fi = ((scale == 0) ? f0in : (scale == 1) ? f1in : f2in)
                              + (size_t)b * NCH * N + n;
            float v[NCH];
            float ss = 0.0f;
#pragma unroll
            for (int c = 0; c < NCH; c++) { v[c] = fi[(size_t)c * N]; ss += v[c] * v[c]; }
            float inv = 1.0f / fmaxf(sqrtf(ss), 1e-12f);
#pragma unroll
            for (int g = 0; g < 8; g++) {
                half8 h;
#pragma unroll
                for (int e = 0; e < 8; e++) {
                    int c = g * 8 + e;
                    h[e] = (c < NCH) ? (_Float16)(v[c] * inv) : (_Float16)0.0f;
                }
                *(half8*)(fo + g * 8) = h;
            }
            const int d = (scale == 0) ? 16 : (scale == 1) ? 8 : 4;
            const int s = 128 / d;
            int i3 = n % d, i2 = (n / d) % d, i1 = n / (d * d);
            int t = target[(size_t)b * VOX + (size_t)(i1 * s) * 16384 + (i2 * s) * 128 + (i3 * s)];
            cls[n] = t;
            myCls = t;
        } else {
            half8 h = {};
#pragma unroll
            for (int g = 0; g < 8; g++) *(half8*)(fo + g * 8) = h;
            cls[n] = 255;
        }
    }
    float* cnt = &acc[12 + (scale * 2 + b) * 16 + 5];
#pragma unroll
    for (int k = 0; k < 3; k++) {
        unsigned long long mb = __ballot(myCls == k);
        if ((threadIdx.x & 63) == 0 && mb)
            atomicAdd(&cnt[k], (float)__popcll(mb));
    }
}

// ---------------- MFMA pair-sum: flat grid, multi-tile blocks ----------------
// 286 blocks: [0,264) -> scale0 (132 blocks/batch x 4 tiles); [264,284) ->
// scale1 (10 tiles/batch, 1 each); [284,286) -> scale2 (1 tile/batch).
// Each block: loop tiles, accumulate s[5] in regs, ONE atomic set at end.
__global__ __launch_bounds__(256) void pair_mfma(const _Float16* __restrict__ Fh0,
                                                 const _Float16* __restrict__ Fh1,
                                                 const _Float16* __restrict__ Fh2,
                                                 const int* __restrict__ cls0,
                                                 const int* __restrict__ cls1,
                                                 const int* __restrict__ cls2,
                                                 float* __restrict__ acc) {
    const int bid = blockIdx.x;
    int z, nt, t0, tstep;
    if (bid < 264) { z = bid / 132; nt = 4; t0 = bid % 132; tstep = 132; }
    else if (bid < 284) { z = 2 + (bid - 264) / 10; nt = 1; t0 = (bid - 264) % 10; tstep = 0; }
    else { z = 4 + (bid - 284); nt = 1; t0 = 0; tstep = 0; }

    const int scale = z >> 1, b = z & 1;
    const int Npad = (scale == 0) ? 4096 : (scale == 1) ? 512 : 128;
    const _Float16* F = ((scale == 0) ? Fh0 : (scale == 1) ? Fh1 : Fh2)
                        + (size_t)b * Npad * 64;
    const int* C = ((scale == 0) ? cls0 : (scale == 1) ? cls1 : cls2) + b * Npad;

    const int tid = threadIdx.x, lane = tid & 63, w = tid >> 6;
    const int wi = w >> 1, wj = w & 1;
    const int m = lane & 15, q = lane >> 4;

    __shared__ int Cis[128], Cjs[128];
    __shared__ float red[4][5];

    float s[5] = {0, 0, 0, 0, 0};

    for (int it = 0; it < nt; it++) {
        int t = t0 + it * tstep;
        // triangular unrank: t -> (bx <= by)
        int by = (int)((sqrtf(8.0f * (float)t + 1.0f) - 1.0f) * 0.5f);
        while ((by + 1) * (by + 2) / 2 <= t) by++;
        while (by * (by + 1) / 2 > t) by--;
        int bx = t - by * (by + 1) / 2;

        const int ib0 = bx * 128, jb0 = by * 128;
        __syncthreads();   // LDS reuse across tiles
        if (tid < 128) Cis[tid] = C[ib0 + tid];
        else           Cjs[tid - 128] = C[jb0 + tid - 128];
        __syncthreads();

        const int ib = ib0 + wi * 64, jb = jb0 + wj * 64;
        const _Float16* Ai = F + (size_t)(ib + m) * 64 + q * 8;
        const _Float16* Bj = F + (size_t)(jb + m) * 64 + q * 8;

        floatx4 acc_[4][4] = {};
#pragma unroll
        for (int k = 0; k < 2; k++) {
            half8 aF[4], bF[4];
#pragma unroll
            for (int t4 = 0; t4 < 4; t4++) {
                aF[t4] = *(const half8*)(Ai + t4 * 16 * 64 + k * 32);
                bF[t4] = *(const half8*)(Bj + t4 * 16 * 64 + k * 32);
            }
#pragma unroll
            for (int ti = 0; ti < 4; ti++)
#pragma unroll
                for (int tj = 0; tj < 4; tj++)
                    acc_[ti][tj] = __builtin_amdgcn_mfma_f32_16x16x32_f16(
                        aF[ti], bF[tj], acc_[ti][tj], 0, 0, 0);
        }

        int cjr[4], cir[4][4];
#pragma unroll
        for (int tj = 0; tj < 4; tj++) cjr[tj] = Cjs[wj * 64 + tj * 16 + m];
#pragma unroll
        for (int ti = 0; ti < 4; ti++)
#pragma unroll
            for (int r = 0; r < 4; r++) cir[ti][r] = Cis[wi * 64 + ti * 16 + q * 4 + r];

#pragma unroll
        for (int ti = 0; ti < 4; ti++) {
#pragma unroll
            for (int tj = 0; tj < 4; tj++) {
#pragma unroll
                for (int r = 0; r < 4; r++) {
                    int gi = ib + ti * 16 + q * 4 + r;
                    int gj = jb + tj * 16 + m;
                    float e = __expf(acc_[ti][tj][r] * 10.0f);
                    bool tri = gi < gj;
                    int ci = cir[ti][r], cj = cjr[tj];
                    int ss = ci + cj, pp = ci * cj;
                    s[0] += (tri && pp == 1) ? e + e : 0.0f;
                    s[1] += (tri && pp == 4) ? e + e : 0.0f;
                    s[2] += (tri && ss == 3) ? e : 0.0f;
                    s[3] += (tri && ss == 1) ? e : 0.0f;
                    s[4] += (tri && ss == 2 && pp == 0) ? e : 0.0f;
                }
            }
        }
    }

#pragma unroll
    for (int k = 0; k < 5; k++) {
        float r = waveSum(s[k]);
        if (lane == 0) red[w][k] = r;
    }
    __syncthreads();
    if (tid < 5) {
        float r = red[0][tid] + red[1][tid] + red[2][tid] + red[3][tid];
        atomicAdd(&acc[12 + z * 16 + tid], r);
    }
}

// ---------------- finalize ---------------------------------------------------
__global__ void finalize_kernel(const float* __restrict__ acc,
                                const float* __restrict__ logits,
                                const int* __restrict__ labels,
                                float* __restrict__ out) {
    if (threadIdx.x != 0 || blockIdx.x != 0) return;
    float dsum = 0.0f;
    for (int b = 0; b < 2; b++)
        for (int c = 0; c < 2; c++) {
            float inter = acc[b * 6 + c];
            float psum  = acc[b * 6 + 2 + c];
            float cnt   = acc[b * 6 + 4 + c];
            dsum += (2.0f * inter + 1e-5f) / (psum + cnt + 1e-5f);
        }
    float dice = 1.0f - dsum * 0.25f;
    float fsum = 0.0f;
    for (int i = 0; i < 6; i++) {
        float x = logits[i];
        float pt = 1.0f / (1.0f + __expf(-x));
        if (labels[i] != 1) pt = 1.0f - pt;
        fsum += -0.25f * (1.0f - pt) * (1.0f - pt) * logf(pt + 1e-6f);
    }
    float focal = fsum * (1.0f / 6.0f);
    const float sw[3] = {1.0f, 0.8f, 0.6f};
    float contr = 0.0f;
    for (int sc = 0; sc < 3; sc++) {
        float bsum = 0.0f;
        for (int b = 0; b < 2; b++) {
            const float* a = &acc[12 + (sc * 2 + b) * 16];
            float S11 = a[0], S22 = a[1], S12 = a[2], S01 = a[3], S02 = a[4];
            float c0 = a[5], c1 = a[6], c2 = a[7];
            float l = 0.0f, cnt, mean;
            cnt = c1 * c1 - c1; mean = S11 / fmaxf(cnt, 1.0f);
            l += (cnt > 0.0f) ? -logf(mean + 1e-6f) : 0.0f;
            cnt = c2 * c2 - c2; mean = S22 / fmaxf(cnt, 1.0f);
            l += (cnt > 0.0f) ? -logf(mean + 1e-6f) : 0.0f;
            cnt = c1 * c2; mean = S12 / fmaxf(cnt, 1.0f);
            l += (cnt > 0.0f) ? log1pf(mean) : 0.0f;
            cnt = c0 * c1; mean = S01 / fmaxf(cnt, 1.0f);
            l += (cnt > 0.0f) ? log1pf(mean) : 0.0f;
            cnt = c0 * c2; mean = S02 / fmaxf(cnt, 1.0f);
            l += (cnt > 0.0f) ? log1pf(mean) : 0.0f;
            bsum += l;
        }
        contr += sw[sc] * bsum * 0.5f;
    }
    float total = dice + focal + 0.1f * contr;
    out[0] = total;
    out[1] = dice;
    out[2] = focal;
    out[3] = contr;
}

// ---------------- launch -----------------------------------------------------
extern "C" void kernel_launch(void* const* d_in, const int* in_sizes, int n_in,
                              void* d_out, int out_size, void* d_ws, size_t ws_size,
                              hipStream_t stream) {
    const float* pred   = (const float*)d_in[0];
    const int*   target = (const int*)d_in[1];
    const float* f0     = (const float*)d_in[2];
    const float* f1     = (const float*)d_in[3];
    const float* f2     = (const float*)d_in[4];
    const float* logits = (const float*)d_in[5];
    const int*   labels = (const int*)d_in[6];
    float* out = (float*)d_out;

    char* ws = (char*)d_ws;
    float* acc = (float*)ws;                         // 128 floats @ 0
    int* cls0 = (int*)(ws + 1024);                   // 2*4096 ints
    int* cls1 = (int*)(ws + 1024 + 32768);           // 2*512 ints
    int* cls2 = (int*)(ws + 1024 + 32768 + 4096);    // 2*128 ints
    _Float16* Fh0 = (_Float16*)(ws + 40960);                      // 2*4096*64
    _Float16* Fh1 = (_Float16*)(ws + 40960 + 1048576);            // 2*512*64
    _Float16* Fh2 = (_Float16*)(ws + 40960 + 1048576 + 131072);   // 2*128*64

    zero_acc<<<dim3(1), dim3(64), 0, stream>>>(acc);
    dice_kernel<<<dim3(512, 1, 2), dim3(256), 0, stream>>>(pred, target, acc);
    norm_kernel<<<dim3(16, 3, 2), dim3(256), 0, stream>>>(f0, f1, f2, target,
                                                          Fh0, Fh1, Fh2,
                                                          cls0, cls1, cls2, acc);
    pair_mfma<<<dim3(286), dim3(256), 0, stream>>>(Fh0, Fh1, Fh2,
                                                   cls0, cls1, cls2, acc);
    finalize_kernel<<<dim3(1), dim3(64), 0, stream>>>(acc, logits, labels, out);
}